// Round 2
// baseline (382.116 us; speedup 1.0000x reference)
//
#include <hip/hip_runtime.h>
#include <stdint.h>
#include <stddef.h>

// Problem constants (AttentiveTransformer: B=65536, D_IN=128, F=512, fp32)
#define NROWS 65536
#define DK 128
#define NF 512
#define BN_EPS 1e-3f

typedef __attribute__((ext_vector_type(8))) short short8;   // 8 x bf16 (4 VGPR)
typedef __attribute__((ext_vector_type(4))) float f32x4;    // MFMA accumulator

__device__ __forceinline__ unsigned short f2bf(float f) {
  unsigned int u = __builtin_bit_cast(unsigned int, f);
  u += 0x7fffu + ((u >> 16) & 1u);     // round-to-nearest-even
  return (unsigned short)(u >> 16);
}
__device__ __forceinline__ float bf2f(unsigned short h) {
  unsigned int u = ((unsigned int)h) << 16;
  return __builtin_bit_cast(float, u);
}

// ---------------------------------------------------------------------------
// Prep: blocks 0..255 transpose W [128][512] -> Wt hi/lo bf16 [512][128],
//       with BN scale alpha = gamma*rsqrt(var+eps) BAKED INTO the columns
//       (W' = W * alpha; z = inp.W' + delta). Block 256 computes delta.
// ---------------------------------------------------------------------------
__global__ void prep_kernel(const float* __restrict__ W,
                            const float* __restrict__ bias,
                            const float* __restrict__ gamma,
                            const float* __restrict__ beta,
                            const float* __restrict__ mean,
                            const float* __restrict__ var,
                            unsigned short* __restrict__ wt_hi,
                            unsigned short* __restrict__ wt_lo,
                            float* __restrict__ delta) {
  int bid = blockIdx.x;
  int tid = threadIdx.x;
  if (bid < 256) {
    int idx = bid * 256 + tid;        // 0..65535 over [128][512]
    int d = idx >> 9;                 // k index 0..127
    int f = idx & 511;                // col index 0..511
    float a = gamma[f] * rsqrtf(var[f] + BN_EPS);
    float w = W[idx] * a;             // fold BN scale into the weight column
    unsigned short wh = f2bf(w);
    float rem = w - bf2f(wh);
    wt_hi[(size_t)f * DK + d] = wh;
    wt_lo[(size_t)f * DK + d] = f2bf(rem);
  } else {
#pragma unroll
    for (int i = 0; i < 2; ++i) {
      int f = tid + i * 256;
      float a = gamma[f] * rsqrtf(var[f] + BN_EPS);
      delta[f] = (bias[f] - mean[f]) * a + beta[f];
    }
  }
}

// ---------------------------------------------------------------------------
// Fused, barrier-free: each WAVE owns 16 rows and computes ALL 512 columns.
// The MFMA C-layout (col = t*16 + (l&15), row = (l>>4)*4 + reg) is then
// already the sparsemax layout: quad q, reg r <-> row q*4+r; lane li, tile t
// <-> col t*16+li. No LDS, no __syncthreads, no cross-wave exchange.
//   Phase 1: A frag (16 rows, split bf16 hi/lo) held in regs; t = 0..31
//            B tiles streamed from L2; 3-product split MFMA; acc[32] f32x4
//            (128 VGPR) kept live end-to-end.
//   Phase 2: z = (acc + delta)*prior in place; Michelot sparsemax run on
//            4 rows per lane IN LOCKSTEP (4-way ILP on the serial chains);
//            4B/lane prior loads & out stores, 64B-coalesced per quad.
// ---------------------------------------------------------------------------
__global__ __launch_bounds__(256, 2) void fused_kernel(
    const float* __restrict__ inp,            // [65536][128]
    const float* __restrict__ prior,          // [65536][512]
    const unsigned short* __restrict__ wt_hi, // [512][128] bf16 hi (alpha-baked)
    const unsigned short* __restrict__ wt_lo, // [512][128] bf16 lo
    const float* __restrict__ delta,          // [512]
    float* __restrict__ out) {                // [65536][512]
  const int tid = threadIdx.x;
  const int w = tid >> 6;        // wave 0..3
  const int l = tid & 63;        // lane
  const int q = l >> 4;          // quad 0..3
  const int li = l & 15;
  const int rbase = blockIdx.x * 64 + w * 16;   // this wave's 16 rows

  // ---- Phase 1a: load + split-convert A fragments (held in regs) ----
  const float* arow = inp + (size_t)(rbase + li) * DK + q * 8;
  short8 ah[4], al[4];
#pragma unroll
  for (int kk = 0; kk < 4; ++kk) {
    float4 v0 = *(const float4*)(arow + kk * 32);
    float4 v1 = *(const float4*)(arow + kk * 32 + 4);
    float av[8] = {v0.x, v0.y, v0.z, v0.w, v1.x, v1.y, v1.z, v1.w};
    short8 h, lo;
#pragma unroll
    for (int j = 0; j < 8; ++j) {
      unsigned short hb = f2bf(av[j]);
      h[j] = (short)hb;
      lo[j] = (short)f2bf(av[j] - bf2f(hb));
    }
    ah[kk] = h;
    al[kk] = lo;
  }

  // ---- Phase 1b: MFMA over all 32 column-tiles, 3-product split ----
  f32x4 acc[32];
#pragma unroll
  for (int t = 0; t < 32; ++t) acc[t] = (f32x4){0.f, 0.f, 0.f, 0.f};

#pragma unroll
  for (int t = 0; t < 32; ++t) {
    const unsigned short* wbh = wt_hi + (size_t)(t * 16 + li) * DK + q * 8;
    const unsigned short* wbl = wt_lo + (size_t)(t * 16 + li) * DK + q * 8;
#pragma unroll
    for (int kk = 0; kk < 4; ++kk) {
      short8 bh = *(const short8*)(wbh + kk * 32);
      short8 bl = *(const short8*)(wbl + kk * 32);
      acc[t] = __builtin_amdgcn_mfma_f32_16x16x32_bf16(ah[kk], bh, acc[t], 0, 0, 0);
      acc[t] = __builtin_amdgcn_mfma_f32_16x16x32_bf16(al[kk], bh, acc[t], 0, 0, 0);
      acc[t] = __builtin_amdgcn_mfma_f32_16x16x32_bf16(ah[kk], bl, acc[t], 0, 0, 0);
    }
  }

  // ---- Phase 2a: z = (acc + delta) * prior, in place ----
  const float* pr0 = prior + (size_t)(rbase + q * 4 + 0) * NF + li;
  const float* pr1 = prior + (size_t)(rbase + q * 4 + 1) * NF + li;
  const float* pr2 = prior + (size_t)(rbase + q * 4 + 2) * NF + li;
  const float* pr3 = prior + (size_t)(rbase + q * 4 + 3) * NF + li;
#pragma unroll
  for (int t = 0; t < 32; ++t) {
    float dt = delta[t * 16 + li];
    acc[t][0] = (acc[t][0] + dt) * pr0[t * 16];
    acc[t][1] = (acc[t][1] + dt) * pr1[t * 16];
    acc[t][2] = (acc[t][2] + dt) * pr2[t * 16];
    acc[t][3] = (acc[t][3] + dt) * pr3[t * 16];
  }

  // ---- Phase 2b: row max (4 rows in lockstep; quad = 16 lanes per row) ----
  float mx[4];
#pragma unroll
  for (int r = 0; r < 4; ++r) mx[r] = acc[0][r];
#pragma unroll
  for (int t = 1; t < 32; ++t)
#pragma unroll
    for (int r = 0; r < 4; ++r) mx[r] = fmaxf(mx[r], acc[t][r]);
#pragma unroll
  for (int off = 1; off <= 8; off <<= 1)
#pragma unroll
    for (int r = 0; r < 4; ++r) mx[r] = fmaxf(mx[r], __shfl_xor(mx[r], off, 64));

  // ---- Phase 2c: Michelot fixed-point, 4 rows in lockstep ----
  float tau[4], cprev[4];
#pragma unroll
  for (int r = 0; r < 4; ++r) { tau[r] = mx[r] - 1.0f; cprev[r] = -1.0f; }
  for (int it = 0; it < 40; ++it) {
    float s[4] = {0.f, 0.f, 0.f, 0.f};
    float c[4] = {0.f, 0.f, 0.f, 0.f};
#pragma unroll
    for (int t = 0; t < 32; ++t) {
#pragma unroll
      for (int r = 0; r < 4; ++r) {
        bool in = acc[t][r] > tau[r];
        s[r] += in ? acc[t][r] : 0.0f;
        c[r] += in ? 1.0f : 0.0f;
      }
    }
#pragma unroll
    for (int off = 1; off <= 8; off <<= 1) {
#pragma unroll
      for (int r = 0; r < 4; ++r) {
        s[r] += __shfl_xor(s[r], off, 64);
        c[r] += __shfl_xor(c[r], off, 64);
      }
    }
#pragma unroll
    for (int r = 0; r < 4; ++r) tau[r] = (s[r] - 1.0f) / c[r];
    bool conv = (c[0] == cprev[0]) & (c[1] == cprev[1]) &
                (c[2] == cprev[2]) & (c[3] == cprev[3]);
    if (__all(conv)) break;   // support fixed -> converged (idempotent)
#pragma unroll
    for (int r = 0; r < 4; ++r) cprev[r] = c[r];
  }

  // ---- Phase 2d: output, 64B-coalesced per quad ----
  float* po0 = out + (size_t)(rbase + q * 4 + 0) * NF + li;
  float* po1 = out + (size_t)(rbase + q * 4 + 1) * NF + li;
  float* po2 = out + (size_t)(rbase + q * 4 + 2) * NF + li;
  float* po3 = out + (size_t)(rbase + q * 4 + 3) * NF + li;
#pragma unroll
  for (int t = 0; t < 32; ++t) {
    po0[t * 16] = fmaxf(acc[t][0] - tau[0], 0.0f);
    po1[t * 16] = fmaxf(acc[t][1] - tau[1], 0.0f);
    po2[t * 16] = fmaxf(acc[t][2] - tau[2], 0.0f);
    po3[t * 16] = fmaxf(acc[t][3] - tau[3], 0.0f);
  }
}

// ---------------------------------------------------------------------------
extern "C" void kernel_launch(void* const* d_in, const int* in_sizes, int n_in,
                              void* d_out, int out_size, void* d_ws, size_t ws_size,
                              hipStream_t stream) {
  const float* inp   = (const float*)d_in[0];   // [65536][128]
  const float* prior = (const float*)d_in[1];   // [65536][512]
  const float* W     = (const float*)d_in[2];   // [128][512]
  const float* bias  = (const float*)d_in[3];   // [512]
  const float* gamma = (const float*)d_in[4];
  const float* beta  = (const float*)d_in[5];
  const float* mean  = (const float*)d_in[6];
  const float* var   = (const float*)d_in[7];
  float* out = (float*)d_out;

  // workspace carve: 131072 + 131072 + 2048 bytes
  unsigned short* wt_hi = (unsigned short*)d_ws;
  unsigned short* wt_lo = wt_hi + (size_t)NF * DK;
  float* delta = (float*)(wt_lo + (size_t)NF * DK);

  prep_kernel<<<257, 256, 0, stream>>>(W, bias, gamma, beta, mean, var,
                                       wt_hi, wt_lo, delta);
  fused_kernel<<<NROWS / 64, 256, 0, stream>>>(inp, prior, wt_hi, wt_lo,
                                               delta, out);
}

// Round 3
// 342.934 us; speedup vs baseline: 1.1143x; 1.1143x over previous
//
#include <hip/hip_runtime.h>
#include <stdint.h>
#include <stddef.h>

// Problem constants (AttentiveTransformer: B=65536, D_IN=128, F=512, fp32)
#define NROWS 65536
#define DK 128
#define NF 512
#define BN_EPS 1e-3f
#define LDP (NF + 4)    // zsh row stride: +4 floats keeps 16B alignment,
                        // spreads phase-1c same-col writes across banks

typedef __attribute__((ext_vector_type(8))) short short8;   // 8 x bf16 (4 VGPR)
typedef __attribute__((ext_vector_type(4))) float f32x4;    // MFMA acc / vec4

__device__ __forceinline__ unsigned short f2bf(float f) {
  unsigned int u = __builtin_bit_cast(unsigned int, f);
  u += 0x7fffu + ((u >> 16) & 1u);     // round-to-nearest-even
  return (unsigned short)(u >> 16);
}
__device__ __forceinline__ float bf2f(unsigned short h) {
  unsigned int u = ((unsigned int)h) << 16;
  return __builtin_bit_cast(float, u);
}

// ---------------------------------------------------------------------------
// Prep: blocks 0..255 transpose W [128][512] -> Wt hi/lo bf16 [512][128],
//       with BN scale alpha = gamma*rsqrt(var+eps) BAKED INTO the columns
//       (z = inp.W' + delta). Block 256 computes delta.
// ---------------------------------------------------------------------------
__global__ void prep_kernel(const float* __restrict__ W,
                            const float* __restrict__ bias,
                            const float* __restrict__ gamma,
                            const float* __restrict__ beta,
                            const float* __restrict__ mean,
                            const float* __restrict__ var,
                            unsigned short* __restrict__ wt_hi,
                            unsigned short* __restrict__ wt_lo,
                            float* __restrict__ delta) {
  int bid = blockIdx.x;
  int tid = threadIdx.x;
  if (bid < 256) {
    int idx = bid * 256 + tid;        // 0..65535 over [128][512]
    int d = idx >> 9;                 // k index 0..127
    int f = idx & 511;                // col index 0..511
    float a = gamma[f] * rsqrtf(var[f] + BN_EPS);
    float w = W[idx] * a;             // fold BN scale into the weight column
    unsigned short wh = f2bf(w);
    float rem = w - bf2f(wh);
    wt_hi[(size_t)f * DK + d] = wh;
    wt_lo[(size_t)f * DK + d] = f2bf(rem);
  } else {
#pragma unroll
    for (int i = 0; i < 2; ++i) {
      int f = tid + i * 256;
      float a = gamma[f] * rsqrtf(var[f] + BN_EPS);
      delta[f] = (bias[f] - mean[f]) * a + beta[f];
    }
  }
}

// ---------------------------------------------------------------------------
// Fused: GEMM (split-bf16 MFMA) + BN -> LDS, then per-row prior*sparsemax.
// Round-0 structure (32 rows/block, 4 waves, 64KiB-class LDS) with:
//  * prior prefetched to REGISTERS at block entry (keep-alive asm fence so
//    the loads cannot be sunk past the MFMA phase) — the 128 MiB prior
//    stream overlaps the GEMM instead of serializing after the barrier.
//  * __launch_bounds__(256,2): 256-VGPR budget so the prefetch can be held.
//  * zsh row stride 516: phase-1c same-col scalar writes 16-way -> 2-way.
//  * alpha baked into Wt (prep), epilogue = fmaf(acc, 1, delta) -> add.
// ---------------------------------------------------------------------------
__global__ __launch_bounds__(256, 2) void fused_kernel(
    const float* __restrict__ inp,            // [65536][128]
    const float* __restrict__ prior,          // [65536][512]
    const unsigned short* __restrict__ wt_hi, // [512][128] bf16 hi (alpha-baked)
    const unsigned short* __restrict__ wt_lo, // [512][128] bf16 lo
    const float* __restrict__ delta,          // [512]
    float* __restrict__ out) {                // [65536][512]
  __shared__ float zsh[32][LDP];              // 64.5 KiB -> 2 blocks/CU

  const int tid = threadIdx.x;
  const int w = tid >> 6;        // wave 0..3
  const int l = tid & 63;        // lane
  const int q = l >> 4;          // quad 0..3
  const int li = l & 15;
  const int r0 = blockIdx.x * 32;
  const int n0 = w * 128;

  // ---- issue A loads (oldest in the vmem queue) ----
  const float* arow0 = inp + (size_t)(r0 + li) * DK + q * 8;
  const float* arow1 = inp + (size_t)(r0 + 16 + li) * DK + q * 8;
  float4 araw[2][8];
#pragma unroll
  for (int kk = 0; kk < 4; ++kk) {
    araw[0][2 * kk + 0] = *(const float4*)(arow0 + kk * 32);
    araw[0][2 * kk + 1] = *(const float4*)(arow0 + kk * 32 + 4);
    araw[1][2 * kk + 0] = *(const float4*)(arow1 + kk * 32);
    araw[1][2 * kk + 1] = *(const float4*)(arow1 + kk * 32 + 4);
  }

  // ---- issue prior prefetch for this thread's two phase-2 rows ----
  const int trow0 = w * 8 + q;          // sub 0 row
  const int trow1 = w * 8 + 4 + q;      // sub 1 row
  const float* prow0 = prior + (size_t)(r0 + trow0) * NF + li * 4;
  const float* prow1 = prior + (size_t)(r0 + trow1) * NF + li * 4;
  f32x4 pv0[8], pv1[8];
#pragma unroll
  for (int j = 0; j < 8; ++j) {
    pv0[j] = *(const f32x4*)(prow0 + 64 * j);
    pv1[j] = *(const f32x4*)(prow1 + 64 * j);
  }
  // keep-alive fence: values must exist in VGPRs HERE -> loads issue (and
  // complete) before the MFMA phase; compiler cannot sink them to phase 2.
#pragma unroll
  for (int j = 0; j < 8; ++j) {
    asm volatile("" : "+v"(pv0[j]));
    asm volatile("" : "+v"(pv1[j]));
  }

  // ---- split-convert A to bf16 hi/lo fragments ----
  short8 ah[2][4], al[2][4];
#pragma unroll
  for (int m = 0; m < 2; ++m) {
#pragma unroll
    for (int kk = 0; kk < 4; ++kk) {
      float av[8] = {araw[m][2 * kk].x,     araw[m][2 * kk].y,
                     araw[m][2 * kk].z,     araw[m][2 * kk].w,
                     araw[m][2 * kk + 1].x, araw[m][2 * kk + 1].y,
                     araw[m][2 * kk + 1].z, araw[m][2 * kk + 1].w};
      short8 h, lo;
#pragma unroll
      for (int j = 0; j < 8; ++j) {
        unsigned short hb = f2bf(av[j]);
        h[j] = (short)hb;
        lo[j] = (short)f2bf(av[j] - bf2f(hb));
      }
      ah[m][kk] = h;
      al[m][kk] = lo;
    }
  }

  // ---- MFMA main loop, 3-product split for ~fp32 accuracy ----
  f32x4 acc[2][8];
#pragma unroll
  for (int m = 0; m < 2; ++m)
#pragma unroll
    for (int t = 0; t < 8; ++t)
      acc[m][t] = (f32x4){0.f, 0.f, 0.f, 0.f};

#pragma unroll
  for (int t = 0; t < 8; ++t) {
    const unsigned short* wbh = wt_hi + (size_t)(n0 + t * 16 + li) * DK + q * 8;
    const unsigned short* wbl = wt_lo + (size_t)(n0 + t * 16 + li) * DK + q * 8;
#pragma unroll
    for (int kk = 0; kk < 4; ++kk) {
      short8 bh = *(const short8*)(wbh + kk * 32);
      short8 bl = *(const short8*)(wbl + kk * 32);
      acc[0][t] = __builtin_amdgcn_mfma_f32_16x16x32_bf16(ah[0][kk], bh, acc[0][t], 0, 0, 0);
      acc[1][t] = __builtin_amdgcn_mfma_f32_16x16x32_bf16(ah[1][kk], bh, acc[1][t], 0, 0, 0);
      acc[0][t] = __builtin_amdgcn_mfma_f32_16x16x32_bf16(al[0][kk], bh, acc[0][t], 0, 0, 0);
      acc[1][t] = __builtin_amdgcn_mfma_f32_16x16x32_bf16(al[1][kk], bh, acc[1][t], 0, 0, 0);
      acc[0][t] = __builtin_amdgcn_mfma_f32_16x16x32_bf16(ah[0][kk], bl, acc[0][t], 0, 0, 0);
      acc[1][t] = __builtin_amdgcn_mfma_f32_16x16x32_bf16(ah[1][kk], bl, acc[1][t], 0, 0, 0);
    }
  }

  // ---- BN epilogue -> LDS ----
#pragma unroll
  for (int t = 0; t < 8; ++t) {
    int col = n0 + t * 16 + li;
    float dl = delta[col];
#pragma unroll
    for (int m = 0; m < 2; ++m) {
#pragma unroll
      for (int r = 0; r < 4; ++r) {
        zsh[m * 16 + q * 4 + r][col] = acc[m][t][r] + dl;
      }
    }
  }
  __syncthreads();

  // ---- Phase 2: per-row prior-scaled sparsemax (quad = one row) ----
#pragma unroll
  for (int sub = 0; sub < 2; ++sub) {
    const int trow = (sub == 0) ? trow0 : trow1;
    const size_t grow = (size_t)(r0 + trow);
    float z[32];
#pragma unroll
    for (int j = 0; j < 8; ++j) {
      f32x4 zv = *(const f32x4*)&zsh[trow][li * 4 + 64 * j];
      f32x4 pv = (sub == 0) ? pv0[j] : pv1[j];
      z[4 * j + 0] = zv[0] * pv[0];
      z[4 * j + 1] = zv[1] * pv[1];
      z[4 * j + 2] = zv[2] * pv[2];
      z[4 * j + 3] = zv[3] * pv[3];
    }
    // row max (reduce over 16-lane group: xor masks 1,2,4,8)
    float mx = z[0];
#pragma unroll
    for (int j = 1; j < 32; ++j) mx = fmaxf(mx, z[j]);
#pragma unroll
    for (int off = 1; off <= 8; off <<= 1) mx = fmaxf(mx, __shfl_xor(mx, off, 64));

    // Michelot fixed-point: tau <- (sum_S - 1)/|S|, S = {z > tau}
    float tau = mx - 1.0f;
    float cprev = -1.0f;
    for (int it = 0; it < 40; ++it) {
      float s = 0.0f, c = 0.0f;
#pragma unroll
      for (int j = 0; j < 32; ++j) {
        bool in = z[j] > tau;
        s += in ? z[j] : 0.0f;
        c += in ? 1.0f : 0.0f;
      }
#pragma unroll
      for (int off = 1; off <= 8; off <<= 1) {
        s += __shfl_xor(s, off, 64);
        c += __shfl_xor(c, off, 64);
      }
      tau = (s - 1.0f) / c;
      if (__all(c == cprev)) break;   // support fixed -> converged (idempotent)
      cprev = c;
    }

    float* orow = out + grow * NF + li * 4;
#pragma unroll
    for (int j = 0; j < 8; ++j) {
      float4 ov;
      ov.x = fmaxf(z[4 * j + 0] - tau, 0.0f);
      ov.y = fmaxf(z[4 * j + 1] - tau, 0.0f);
      ov.z = fmaxf(z[4 * j + 2] - tau, 0.0f);
      ov.w = fmaxf(z[4 * j + 3] - tau, 0.0f);
      *(float4*)(orow + 64 * j) = ov;
    }
  }
}

// ---------------------------------------------------------------------------
extern "C" void kernel_launch(void* const* d_in, const int* in_sizes, int n_in,
                              void* d_out, int out_size, void* d_ws, size_t ws_size,
                              hipStream_t stream) {
  const float* inp   = (const float*)d_in[0];   // [65536][128]
  const float* prior = (const float*)d_in[1];   // [65536][512]
  const float* W     = (const float*)d_in[2];   // [128][512]
  const float* bias  = (const float*)d_in[3];   // [512]
  const float* gamma = (const float*)d_in[4];
  const float* beta  = (const float*)d_in[5];
  const float* mean  = (const float*)d_in[6];
  const float* var   = (const float*)d_in[7];
  float* out = (float*)d_out;

  // workspace carve: 131072 + 131072 + 2048 bytes
  unsigned short* wt_hi = (unsigned short*)d_ws;
  unsigned short* wt_lo = wt_hi + (size_t)NF * DK;
  float* delta = (float*)(wt_lo + (size_t)NF * DK);

  prep_kernel<<<257, 256, 0, stream>>>(W, bias, gamma, beta, mean, var,
                                       wt_hi, wt_lo, delta);
  fused_kernel<<<NROWS / 32, 256, 0, stream>>>(inp, prior, wt_hi, wt_lo,
                                               delta, out);
}